// Round 2
// baseline (200.164 us; speedup 1.0000x reference)
//
#include <hip/hip_runtime.h>
#include <math.h>

#define L 1024
#define NB 32
#define DD 256
#define LAM_F 0.2f
#define EPS_F 1e-7f

#define NDBLK (NB * (L / 16))            // 2048 compute blocks (16 rows each)
#define FILLBLK (NB * L * L / 4 / 1024)  // 8192 zero-fill blocks (float4 x 1024 thr)

__device__ __forceinline__ float wave_sum(float v) {
#pragma unroll
    for (int m = 1; m < 64; m <<= 1) v += __shfl_xor(v, m, 64);
    return v;
}
__device__ __forceinline__ float wave_max(float v) {
#pragma unroll
    for (int m = 1; m < 64; m <<= 1) v = fmaxf(v, __shfl_xor(v, m, 64));
    return v;
}
__device__ __forceinline__ float dot4(float4 a, float4 b) {
    return a.x * b.x + a.y * b.y + a.z * b.z + a.w * b.w;
}

// Kernel A: fused (norms + band dots) and zero-fill of the (B,L,L) output.
// Compute blocks: one item b, 16 rows i0..i0+15; stage 20 y-rows in LDS so m2
// is fetched ~1.25x instead of 5x. Fill blocks: float4 zeros over all of P.
__global__ void __launch_bounds__(1024) prep_kernel(
        const float* __restrict__ m1, const float* __restrict__ m2,
        float* __restrict__ dots, float* __restrict__ xn2o, float* __restrict__ yn2o,
        float* __restrict__ out) {
    if (blockIdx.x >= NDBLK) {
        size_t t = (size_t)(blockIdx.x - NDBLK) * 1024 + threadIdx.x;
        ((float4*)out)[t] = make_float4(0.f, 0.f, 0.f, 0.f);
        return;
    }
    __shared__ float ysh[20 * DD];  // rows i0-2 .. i0+17
    const int b = blockIdx.x >> 6;
    const int i0 = (blockIdx.x & 63) << 4;
    for (int f = threadIdx.x; f < 20 * (DD / 4); f += 1024) {
        int srow = f >> 6, l4 = f & 63;
        int j = i0 - 2 + srow;
        if (j >= 0 && j < L)
            ((float4*)ysh)[f] = ((const float4*)(m2 + (size_t)(j * NB + b) * DD))[l4];
    }
    __syncthreads();
    const int w = threadIdx.x >> 6, lane = threadIdx.x & 63;
    const int i = i0 + w;
    const float4 xv = ((const float4*)(m1 + (size_t)(i * NB + b) * DD))[lane];
    float xn2 = dot4(xv, xv);
    const float4 yself = ((const float4*)(ysh + (w + 2) * DD))[lane];
    float yn2 = dot4(yself, yself);
    float dt[5];
#pragma unroll
    for (int o = 0; o < 5; ++o) {
        int j = i + o - 2;
        float d = 0.f;
        if (j >= 0 && j < L) {
            const float4 y2 = ((const float4*)(ysh + (w + o) * DD))[lane];
            d = dot4(xv, y2);
        }
        dt[o] = d;
    }
    xn2 = wave_sum(xn2);
    yn2 = wave_sum(yn2);
#pragma unroll
    for (int o = 0; o < 5; ++o) dt[o] = wave_sum(dt[o]);
    if (lane == 0) {
        const int r = b * L + i;
        xn2o[r] = xn2;
        yn2o[r] = yn2;
#pragma unroll
        for (int o = 0; o < 5; ++o) dots[r * 5 + o] = dt[o];
    }
}

// Kernel B: one wave per item; lane owns 16 consecutive rows. P factorizes as
// P0[i][o] * sacc[i] (row scale), so each Sinkhorn iteration is pure register
// math + 4 halo shuffles. No LDS, no barriers. Band + cost written straight
// into d_out (zeros were laid down by prep_kernel).
__global__ void __launch_bounds__(64) sinkhorn_kernel(
        const float* __restrict__ dots, const float* __restrict__ xn2,
        const float* __restrict__ yn2, const int* __restrict__ lengths,
        float* __restrict__ out) {
    const int b = blockIdx.x;
    const int lane = threadIdx.x;  // 0..63
    const int l = lengths[b];
    const float rmarg = 1.0f / (float)l;
    const int r0 = lane << 4;

    float inv_nx[16], inv_ny[16];
#pragma unroll
    for (int k = 0; k < 16; ++k) {
        const int base = b * L + r0 + k;
        inv_nx[k] = 1.0f / fmaxf(sqrtf(xn2[base]), 1e-5f);
        inv_ny[k] = 1.0f / fmaxf(sqrtf(yn2[base]), 1e-5f);
    }
    // halo of inv_ny: rows r0-2, r0-1, r0+16, r0+17
    float nyext[20];
    nyext[0] = __shfl_up(inv_ny[14], 1, 64);
    nyext[1] = __shfl_up(inv_ny[15], 1, 64);
#pragma unroll
    for (int k = 0; k < 16; ++k) nyext[k + 2] = inv_ny[k];
    nyext[18] = __shfl_down(inv_ny[0], 1, 64);
    nyext[19] = __shfl_down(inv_ny[1], 1, 64);

    float P0[16][5], p0sum[16], pm0[16];
#pragma unroll
    for (int k = 0; k < 16; ++k) {
        const int i = r0 + k;
        const int base = b * L + i;
        p0sum[k] = 0.f;
        pm0[k] = 0.f;
#pragma unroll
        for (int o = 0; o < 5; ++o) {
            const int j = i + o - 2;
            const float dv = dots[base * 5 + o];
            const float M = 1.0f - dv * inv_nx[k] * nyext[k + o];
            const bool valid = (j >= 0) && (j < L) && (i < l) && (j < l);
            const float P = valid ? expf(-LAM_F * M) : 0.0f;
            P0[k][o] = P;
            p0sum[k] += P;
            pm0[k] += P * M;  // P==0 kills invalid entries; M always finite
        }
    }
    // initial P /= sum(P)
    float tot = 0.f;
#pragma unroll
    for (int k = 0; k < 16; ++k) tot += p0sum[k];
    tot = wave_sum(tot);
    const float inv_total = 1.0f / tot;
    float sacc[16], u[16];
#pragma unroll
    for (int k = 0; k < 16; ++k) { sacc[k] = inv_total; u[k] = 0.f; }

    // halo of the (constant) P0 entries needed by column sums
    const float pA = __shfl_up(P0[14][4], 1, 64);   // row r0-2, col 4
    const float pB = __shfl_up(P0[15][3], 1, 64);   // row r0-1, col 3
    const float pC = __shfl_up(P0[15][4], 1, 64);   // row r0-1, col 4
    const float pE = __shfl_down(P0[0][0], 1, 64);  // row r0+16, col 0
    const float pD = __shfl_down(P0[0][1], 1, 64);  // row r0+16, col 1
    const float pF = __shfl_down(P0[1][0], 1, 64);  // row r0+17, col 0

    for (int it = 0; it < 10; ++it) {
        float us[16], diff = 0.f;
#pragma unroll
        for (int k = 0; k < 16; ++k) {
            us[k] = p0sum[k] * sacc[k];
            diff = fmaxf(diff, fabsf(u[k] - us[k]));
        }
        diff = wave_max(diff);
        if (diff <= EPS_F) break;  // cond false -> frozen forever (faithful)

        float s1[16];
#pragma unroll
        for (int k = 0; k < 16; ++k) {
            u[k] = us[k];
            const float sr = (r0 + k < l) ? rmarg / us[k] : 0.0f;
            s1[k] = sacc[k] * sr;  // row-scaled accumulator (P1 = P0*s1)
        }
        // halo of s1 (zeroed at wave edges == rows outside [0,L))
        float s1ext[20];
        {
            float a = __shfl_up(s1[14], 1, 64), c = __shfl_up(s1[15], 1, 64);
            float d = __shfl_down(s1[0], 1, 64), e = __shfl_down(s1[1], 1, 64);
            s1ext[0] = (lane == 0) ? 0.f : a;
            s1ext[1] = (lane == 0) ? 0.f : c;
            s1ext[18] = (lane == 63) ? 0.f : d;
            s1ext[19] = (lane == 63) ? 0.f : e;
        }
#pragma unroll
        for (int k = 0; k < 16; ++k) s1ext[k + 2] = s1[k];

        // column sums s[j=r0+k] = sum_d P1[j+d][2-d]
        float s[16];
#pragma unroll
        for (int k = 0; k < 16; ++k) {
            float acc = P0[k][2] * s1ext[k + 2];
            acc += ((k >= 2) ? P0[k - 2][4] : ((k == 0) ? pA : pC)) * s1ext[k];
            acc += ((k >= 1) ? P0[k - 1][3] : pB) * s1ext[k + 1];
            acc += ((k <= 14) ? P0[k + 1][1] : pD) * s1ext[k + 3];
            acc += ((k <= 13) ? P0[k + 2][0] : ((k == 14) ? pE : pF)) * s1ext[k + 4];
            s[k] = acc;
        }
#pragma unroll
        for (int k = 0; k < 16; ++k) {
            const float sc = (r0 + k < l) ? rmarg / s[k] : 0.0f;  // along ROWS (faithful)
            sacc[k] = s1[k] * sc;
        }
    }

    // epilogue: rowsums, cost, band write
    float rs[16];
#pragma unroll
    for (int k = 0; k < 16; ++k) rs[k] = (r0 + k < l) ? p0sum[k] * sacc[k] : 1.0f;
    float rsext[20];
    rsext[0] = __shfl_up(rs[14], 1, 64);
    rsext[1] = __shfl_up(rs[15], 1, 64);
#pragma unroll
    for (int k = 0; k < 16; ++k) rsext[k + 2] = rs[k];
    rsext[18] = __shfl_down(rs[0], 1, 64);
    rsext[19] = __shfl_down(rs[1], 1, 64);

    float cpart = 0.f;
#pragma unroll
    for (int k = 0; k < 16; ++k) cpart += pm0[k] * sacc[k];
    cpart = wave_sum(cpart);
    if (lane == 0) out[(size_t)NB * L * L + b] = cpart;

#pragma unroll
    for (int k = 0; k < 16; ++k) {
        const int i = r0 + k;
        // P_norm[i][j] = P[i][j] / rs[j]   (column-indexed rowsum, faithful)
        const float pv0 = P0[k][0] * sacc[k] / rsext[k + 0];
        const float pv1 = P0[k][1] * sacc[k] / rsext[k + 1];
        const float pv2 = P0[k][2] * sacc[k] / rsext[k + 2];
        const float pv3 = P0[k][3] * sacc[k] / rsext[k + 3];
        const float pv4 = P0[k][4] * sacc[k] / rsext[k + 4];
        const int c0 = (i - 2 > 0 ? i - 2 : 0) >> 2;
        const int c1 = (i + 2 < L - 1 ? i + 2 : L - 1) >> 2;
        float4* orow = (float4*)(out + ((size_t)b * L + i) * L);
        for (int c = c0; c <= c1; ++c) {
            float e[4];
#pragma unroll
            for (int t = 0; t < 4; ++t) {
                const int o = 4 * c + t - i + 2;
                e[t] = (o == 0) ? pv0 : (o == 1) ? pv1 : (o == 2) ? pv2
                       : (o == 3) ? pv3 : (o == 4) ? pv4 : 0.0f;
            }
            orow[c] = make_float4(e[0], e[1], e[2], e[3]);
        }
    }
}

extern "C" void kernel_launch(void* const* d_in, const int* in_sizes, int n_in,
                              void* d_out, int out_size, void* d_ws, size_t ws_size,
                              hipStream_t stream) {
    const float* m1 = (const float*)d_in[0];
    const float* m2 = (const float*)d_in[1];
    const int* lengths = (const int*)d_in[2];
    float* out = (float*)d_out;
    float* ws = (float*)d_ws;

    float* dots = ws;                  // B*L*5
    float* xn2 = dots + NB * L * 5;    // B*L
    float* yn2 = xn2 + NB * L;         // B*L

    prep_kernel<<<NDBLK + FILLBLK, 1024, 0, stream>>>(m1, m2, dots, xn2, yn2, out);
    sinkhorn_kernel<<<NB, 64, 0, stream>>>(dots, xn2, yn2, lengths, out);
}

// Round 3
// 197.536 us; speedup vs baseline: 1.0133x; 1.0133x over previous
//
#include <hip/hip_runtime.h>
#include <math.h>

#define L 1024
#define NB 32
#define DD 256
#define LAM_F 0.2f
#define EPS_F 1e-7f

#define NDBLK (NB * (L / 16))   // 2048 dots blocks (16 rows each)
#define NSINK NB                // 32 sinkhorn blocks (first in grid)
#define NFILL 8192              // fill blocks: 1024 float4 each (16 iters x 64 lanes)

__device__ __forceinline__ float wave_sum(float v) {
#pragma unroll
    for (int m = 1; m < 64; m <<= 1) v += __shfl_xor(v, m, 64);
    return v;
}
__device__ __forceinline__ float wave_max(float v) {
#pragma unroll
    for (int m = 1; m < 64; m <<= 1) v = fmaxf(v, __shfl_xor(v, m, 64));
    return v;
}
__device__ __forceinline__ float dot4(float4 a, float4 b) {
    return a.x * b.x + a.y * b.y + a.z * b.z + a.w * b.w;
}

// Kernel 1: norms + band dots. One item b, 16 rows per block; 20 y-rows staged
// in LDS (m2 fetched 1.25x). Pure-read kernel (~151 MB).
__global__ void __launch_bounds__(1024) dots_kernel(
        const float* __restrict__ m1, const float* __restrict__ m2,
        float* __restrict__ dots, float* __restrict__ xn2o, float* __restrict__ yn2o) {
    __shared__ float ysh[20 * DD];  // rows i0-2 .. i0+17
    const int b = blockIdx.x >> 6;
    const int i0 = (blockIdx.x & 63) << 4;
    for (int f = threadIdx.x; f < 20 * (DD / 4); f += 1024) {
        int srow = f >> 6, l4 = f & 63;
        int j = i0 - 2 + srow;
        if (j >= 0 && j < L)
            ((float4*)ysh)[f] = ((const float4*)(m2 + (size_t)(j * NB + b) * DD))[l4];
    }
    __syncthreads();
    const int w = threadIdx.x >> 6, lane = threadIdx.x & 63;
    const int i = i0 + w;
    const float4 xv = ((const float4*)(m1 + (size_t)(i * NB + b) * DD))[lane];
    float xn2 = dot4(xv, xv);
    const float4 yself = ((const float4*)(ysh + (w + 2) * DD))[lane];
    float yn2 = dot4(yself, yself);
    float dt[5];
#pragma unroll
    for (int o = 0; o < 5; ++o) {
        int j = i + o - 2;
        float d = 0.f;
        if (j >= 0 && j < L) {
            const float4 y2 = ((const float4*)(ysh + (w + o) * DD))[lane];
            d = dot4(xv, y2);
        }
        dt[o] = d;
    }
    xn2 = wave_sum(xn2);
    yn2 = wave_sum(yn2);
#pragma unroll
    for (int o = 0; o < 5; ++o) dt[o] = wave_sum(dt[o]);
    if (lane == 0) {
        const int r = b * L + i;
        xn2o[r] = xn2;
        yn2o[r] = yn2;
#pragma unroll
        for (int o = 0; o < 5; ++o) dots[r * 5 + o] = dt[o];
    }
}

// Kernel 2: blocks 0..31 = banded Sinkhorn (one wave per item, register-only,
// writes the band float4s + cost). Blocks 32.. = zero-fill of everything NOT
// written by sinkhorn (disjoint addresses -> concurrent, race-free).
__global__ void __launch_bounds__(64) solve_fill_kernel(
        const float* __restrict__ dots, const float* __restrict__ xn2,
        const float* __restrict__ yn2, const int* __restrict__ lengths,
        float* __restrict__ out) {
    const int lane = threadIdx.x;

    if (blockIdx.x >= NSINK) {
        // ---- fill path: 1024 float4 per block, skip band columns ----
        const int t0 = (blockIdx.x - NSINK) << 10;
#pragma unroll
        for (int k = 0; k < 16; ++k) {
            const int t = t0 + (k << 6) + lane;     // float4 index into P
            const int rem = t & 262143;             // within one (L,L) item
            const int i = rem >> 8;
            const int c = rem & 255;
            const int c0 = ((i - 2 > 0) ? i - 2 : 0) >> 2;
            const int c1 = ((i + 2 < L - 1) ? i + 2 : L - 1) >> 2;
            if (c < c0 || c > c1)
                ((float4*)out)[t] = make_float4(0.f, 0.f, 0.f, 0.f);
        }
        return;
    }

    // ---- sinkhorn path: lane owns 16 consecutive rows of item b ----
    const int b = blockIdx.x;
    const int l = lengths[b];
    const float rmarg = 1.0f / (float)l;
    const int r0 = lane << 4;

    float inv_nx[16], inv_ny[16];
#pragma unroll
    for (int k = 0; k < 16; ++k) {
        const int base = b * L + r0 + k;
        inv_nx[k] = 1.0f / fmaxf(sqrtf(xn2[base]), 1e-5f);
        inv_ny[k] = 1.0f / fmaxf(sqrtf(yn2[base]), 1e-5f);
    }
    float nyext[20];
    nyext[0] = __shfl_up(inv_ny[14], 1, 64);
    nyext[1] = __shfl_up(inv_ny[15], 1, 64);
#pragma unroll
    for (int k = 0; k < 16; ++k) nyext[k + 2] = inv_ny[k];
    nyext[18] = __shfl_down(inv_ny[0], 1, 64);
    nyext[19] = __shfl_down(inv_ny[1], 1, 64);

    float P0[16][5], p0sum[16], pm0[16];
#pragma unroll
    for (int k = 0; k < 16; ++k) {
        const int i = r0 + k;
        const int base = b * L + i;
        p0sum[k] = 0.f;
        pm0[k] = 0.f;
#pragma unroll
        for (int o = 0; o < 5; ++o) {
            const int j = i + o - 2;
            const float dv = dots[base * 5 + o];
            const float M = 1.0f - dv * inv_nx[k] * nyext[k + o];
            const bool valid = (j >= 0) && (j < L) && (i < l) && (j < l);
            const float P = valid ? expf(-LAM_F * M) : 0.0f;
            P0[k][o] = P;
            p0sum[k] += P;
            pm0[k] += P * M;
        }
    }
    float tot = 0.f;
#pragma unroll
    for (int k = 0; k < 16; ++k) tot += p0sum[k];
    tot = wave_sum(tot);
    const float inv_total = 1.0f / tot;
    float sacc[16], u[16];
#pragma unroll
    for (int k = 0; k < 16; ++k) { sacc[k] = inv_total; u[k] = 0.f; }

    const float pA = __shfl_up(P0[14][4], 1, 64);   // row r0-2, col 4
    const float pB = __shfl_up(P0[15][3], 1, 64);   // row r0-1, col 3
    const float pC = __shfl_up(P0[15][4], 1, 64);   // row r0-1, col 4
    const float pE = __shfl_down(P0[0][0], 1, 64);  // row r0+16, col 0
    const float pD = __shfl_down(P0[0][1], 1, 64);  // row r0+16, col 1
    const float pF = __shfl_down(P0[1][0], 1, 64);  // row r0+17, col 0

    for (int it = 0; it < 10; ++it) {
        float us[16], diff = 0.f;
#pragma unroll
        for (int k = 0; k < 16; ++k) {
            us[k] = p0sum[k] * sacc[k];
            diff = fmaxf(diff, fabsf(u[k] - us[k]));
        }
        diff = wave_max(diff);
        if (diff <= EPS_F) break;  // cond false -> frozen forever (faithful)

        float s1[16];
#pragma unroll
        for (int k = 0; k < 16; ++k) {
            u[k] = us[k];
            const float sr = (r0 + k < l) ? rmarg / us[k] : 0.0f;
            s1[k] = sacc[k] * sr;
        }
        float s1ext[20];
        {
            float a = __shfl_up(s1[14], 1, 64), c = __shfl_up(s1[15], 1, 64);
            float d = __shfl_down(s1[0], 1, 64), e = __shfl_down(s1[1], 1, 64);
            s1ext[0] = (lane == 0) ? 0.f : a;
            s1ext[1] = (lane == 0) ? 0.f : c;
            s1ext[18] = (lane == 63) ? 0.f : d;
            s1ext[19] = (lane == 63) ? 0.f : e;
        }
#pragma unroll
        for (int k = 0; k < 16; ++k) s1ext[k + 2] = s1[k];

        float s[16];
#pragma unroll
        for (int k = 0; k < 16; ++k) {
            float acc = P0[k][2] * s1ext[k + 2];
            acc += ((k >= 2) ? P0[k - 2][4] : ((k == 0) ? pA : pC)) * s1ext[k];
            acc += ((k >= 1) ? P0[k - 1][3] : pB) * s1ext[k + 1];
            acc += ((k <= 14) ? P0[k + 1][1] : pD) * s1ext[k + 3];
            acc += ((k <= 13) ? P0[k + 2][0] : ((k == 14) ? pE : pF)) * s1ext[k + 4];
            s[k] = acc;
        }
#pragma unroll
        for (int k = 0; k < 16; ++k) {
            const float sc = (r0 + k < l) ? rmarg / s[k] : 0.0f;  // along ROWS (faithful)
            sacc[k] = s1[k] * sc;
        }
    }

    float rs[16];
#pragma unroll
    for (int k = 0; k < 16; ++k) rs[k] = (r0 + k < l) ? p0sum[k] * sacc[k] : 1.0f;
    float rsext[20];
    rsext[0] = __shfl_up(rs[14], 1, 64);
    rsext[1] = __shfl_up(rs[15], 1, 64);
#pragma unroll
    for (int k = 0; k < 16; ++k) rsext[k + 2] = rs[k];
    rsext[18] = __shfl_down(rs[0], 1, 64);
    rsext[19] = __shfl_down(rs[1], 1, 64);

    float cpart = 0.f;
#pragma unroll
    for (int k = 0; k < 16; ++k) cpart += pm0[k] * sacc[k];
    cpart = wave_sum(cpart);
    if (lane == 0) out[(size_t)NB * L * L + b] = cpart;

#pragma unroll
    for (int k = 0; k < 16; ++k) {
        const int i = r0 + k;
        const float pv0 = P0[k][0] * sacc[k] / rsext[k + 0];
        const float pv1 = P0[k][1] * sacc[k] / rsext[k + 1];
        const float pv2 = P0[k][2] * sacc[k] / rsext[k + 2];
        const float pv3 = P0[k][3] * sacc[k] / rsext[k + 3];
        const float pv4 = P0[k][4] * sacc[k] / rsext[k + 4];
        const int c0 = ((i - 2 > 0) ? i - 2 : 0) >> 2;
        const int c1 = ((i + 2 < L - 1) ? i + 2 : L - 1) >> 2;
        float4* orow = (float4*)(out + ((size_t)b * L + i) * L);
        for (int c = c0; c <= c1; ++c) {
            float e[4];
#pragma unroll
            for (int t = 0; t < 4; ++t) {
                const int o = 4 * c + t - i + 2;
                e[t] = (o == 0) ? pv0 : (o == 1) ? pv1 : (o == 2) ? pv2
                       : (o == 3) ? pv3 : (o == 4) ? pv4 : 0.0f;
            }
            orow[c] = make_float4(e[0], e[1], e[2], e[3]);
        }
    }
}

extern "C" void kernel_launch(void* const* d_in, const int* in_sizes, int n_in,
                              void* d_out, int out_size, void* d_ws, size_t ws_size,
                              hipStream_t stream) {
    const float* m1 = (const float*)d_in[0];
    const float* m2 = (const float*)d_in[1];
    const int* lengths = (const int*)d_in[2];
    float* out = (float*)d_out;
    float* ws = (float*)d_ws;

    float* dots = ws;                  // B*L*5
    float* xn2 = dots + NB * L * 5;    // B*L
    float* yn2 = xn2 + NB * L;         // B*L

    dots_kernel<<<NDBLK, 1024, 0, stream>>>(m1, m2, dots, xn2, yn2);
    solve_fill_kernel<<<NSINK + NFILL, 64, 0, stream>>>(dots, xn2, yn2, lengths, out);
}